// Round 1
// baseline (6674.949 us; speedup 1.0000x reference)
//
#include <hip/hip_runtime.h>
#include <hip/hip_bf16.h>
#include <math.h>

#define NN   50000
#define EE   800000
#define ETOT (EE + NN)
#define KDIM 256
#define HEADS 4
#define HIDD 64

// ---------------------------------------------------------------------------
// GEMM: C[m][c] = sum_k A[m][k] * W[c][k]  (+ optional bias0[c] + bias1[c])
// A: [Mrows, 256], W: [ncols, 256], C: [Mrows, ncols]; ncols multiple of 64.
// Tile 64x64, BK=64, 256 threads, 4x4 register tile per thread.
// ---------------------------------------------------------------------------
#define BM 64
#define BN 64
#define BKT 64

__global__ __launch_bounds__(256) void gemm_tn(
    const float* __restrict__ A, const float* __restrict__ W,
    float* __restrict__ C, int Mrows, int ncols,
    const float* __restrict__ bias0, const float* __restrict__ bias1)
{
    __shared__ float As[BKT][BM + 4];   // As[k][r]  (stride 68 floats, 16B aligned)
    __shared__ float Bs[BKT][BN + 4];   // Bs[k][c]

    const int tid = threadIdx.x;
    const int rg = tid >> 4;            // 0..15 -> rows rg*4..rg*4+3
    const int cg = tid & 15;            // 0..15 -> cols cg*4..cg*4+3
    const int n0 = blockIdx.x * BM;
    const int c0 = blockIdx.y * BN;

    float acc[4][4];
    #pragma unroll
    for (int i = 0; i < 4; i++)
        #pragma unroll
        for (int j = 0; j < 4; j++) acc[i][j] = 0.f;

    for (int k0 = 0; k0 < KDIM; k0 += BKT) {
        // ---- load A tile (64 rows x 64 k) as 1024 float4 ----
        #pragma unroll
        for (int i = 0; i < 4; i++) {
            int f  = tid + 256 * i;
            int r  = f >> 4;            // 0..63
            int kq = f & 15;            // float4 slot along k
            float4 v = make_float4(0.f, 0.f, 0.f, 0.f);
            int gr = n0 + r;
            if (gr < Mrows)
                v = *reinterpret_cast<const float4*>(A + (size_t)gr * KDIM + k0 + kq * 4);
            As[kq * 4 + 0][r] = v.x;
            As[kq * 4 + 1][r] = v.y;
            As[kq * 4 + 2][r] = v.z;
            As[kq * 4 + 3][r] = v.w;
        }
        // ---- load B tile: Bs[k][c] = W[c0+c][k0+k] ----
        #pragma unroll
        for (int i = 0; i < 4; i++) {
            int f  = tid + 256 * i;
            int c  = f >> 4;            // 0..63 (ncols multiple of 64 -> always valid)
            int kq = f & 15;
            float4 v = *reinterpret_cast<const float4*>(W + (size_t)(c0 + c) * KDIM + k0 + kq * 4);
            Bs[kq * 4 + 0][c] = v.x;
            Bs[kq * 4 + 1][c] = v.y;
            Bs[kq * 4 + 2][c] = v.z;
            Bs[kq * 4 + 3][c] = v.w;
        }
        __syncthreads();

        #pragma unroll 16
        for (int k = 0; k < BKT; k++) {
            float4 a = *reinterpret_cast<const float4*>(&As[k][rg * 4]);
            float4 b = *reinterpret_cast<const float4*>(&Bs[k][cg * 4]);
            acc[0][0] += a.x * b.x; acc[0][1] += a.x * b.y; acc[0][2] += a.x * b.z; acc[0][3] += a.x * b.w;
            acc[1][0] += a.y * b.x; acc[1][1] += a.y * b.y; acc[1][2] += a.y * b.z; acc[1][3] += a.y * b.w;
            acc[2][0] += a.z * b.x; acc[2][1] += a.z * b.y; acc[2][2] += a.z * b.z; acc[2][3] += a.z * b.w;
            acc[3][0] += a.w * b.x; acc[3][1] += a.w * b.y; acc[3][2] += a.w * b.z; acc[3][3] += a.w * b.w;
        }
        __syncthreads();
    }

    // ---- epilogue ----
    #pragma unroll
    for (int i = 0; i < 4; i++) {
        int gr = n0 + rg * 4 + i;
        if (gr >= Mrows) continue;
        float4 v = make_float4(acc[i][0], acc[i][1], acc[i][2], acc[i][3]);
        int gc = c0 + cg * 4;
        if (bias0) { v.x += bias0[gc + 0]; v.y += bias0[gc + 1]; v.z += bias0[gc + 2]; v.w += bias0[gc + 3]; }
        if (bias1) { v.x += bias1[gc + 0]; v.y += bias1[gc + 1]; v.z += bias1[gc + 2]; v.w += bias1[gc + 3]; }
        *reinterpret_cast<float4*>(C + (size_t)gr * ncols + gc) = v;
    }
}

// ---------------------------------------------------------------------------
// Per-node attention terms: AS[n][h] = sum_c H[n][h*64+c]*a_src[h*64+c], same AD.
// One wave per node, 4 nodes per 256-thread block.
// ---------------------------------------------------------------------------
__global__ __launch_bounds__(256) void alphas_k(
    const float* __restrict__ H, const float* __restrict__ a_src,
    const float* __restrict__ a_dst, float* __restrict__ AS, float* __restrict__ AD)
{
    int wave = threadIdx.x >> 6;
    int lane = threadIdx.x & 63;
    int n = blockIdx.x * 4 + wave;
    if (n >= NN) return;
    const float* hrow = H + (size_t)n * 256;
    #pragma unroll
    for (int h = 0; h < HEADS; h++) {
        float v = hrow[h * 64 + lane];
        float s = v * a_src[h * 64 + lane];
        float d = v * a_dst[h * 64 + lane];
        #pragma unroll
        for (int m = 32; m >= 1; m >>= 1) {
            s += __shfl_xor(s, m, 64);
            d += __shfl_xor(d, m, 64);
        }
        if (lane == 0) { AS[n * 4 + h] = s; AD[n * 4 + h] = d; }
    }
}

// ---------------------------------------------------------------------------
// Init: ACC = 0 (N*256), M = -inf, DEN = 0 (N*4). Grid = NN blocks x 256.
// ---------------------------------------------------------------------------
__global__ __launch_bounds__(256) void init_k(
    float* __restrict__ ACC, float* __restrict__ M, float* __restrict__ DEN)
{
    int i = blockIdx.x * 256 + threadIdx.x;
    ACC[i] = 0.f;
    if (i < NN * 4) { M[i] = -__builtin_inff(); DEN[i] = 0.f; }
}

__device__ __forceinline__ float lrelu(float x) { return x >= 0.f ? x : 0.2f * x; }

__device__ __forceinline__ void atomicMaxFloat(float* addr, float v) {
    // Valid given init to -inf; softmax is shift-invariant so -0.0 corner is harmless.
    if (v >= 0.f) atomicMax(reinterpret_cast<int*>(addr), __float_as_int(v));
    else          atomicMin(reinterpret_cast<unsigned int*>(addr), __float_as_uint(v));
}

// ---------------------------------------------------------------------------
// Segment max of leaky_relu(alpha_s[src]+alpha_d[dst]) over dst. 1 thread/edge.
// ---------------------------------------------------------------------------
__global__ __launch_bounds__(256) void edge_max_k(
    const int* __restrict__ ei, const float* __restrict__ AS,
    const float* __restrict__ AD, float* __restrict__ M)
{
    int e = blockIdx.x * 256 + threadIdx.x;
    if (e >= ETOT) return;
    int src, dst;
    if (e < EE) { src = ei[e]; dst = ei[EE + e]; }
    else        { src = dst = e - EE; }
    float4 s4 = *reinterpret_cast<const float4*>(AS + (size_t)src * 4);
    float4 d4 = *reinterpret_cast<const float4*>(AD + (size_t)dst * 4);
    atomicMaxFloat(M + (size_t)dst * 4 + 0, lrelu(s4.x + d4.x));
    atomicMaxFloat(M + (size_t)dst * 4 + 1, lrelu(s4.y + d4.y));
    atomicMaxFloat(M + (size_t)dst * 4 + 2, lrelu(s4.z + d4.z));
    atomicMaxFloat(M + (size_t)dst * 4 + 3, lrelu(s4.w + d4.w));
}

// ---------------------------------------------------------------------------
// Scatter: w[h] = exp(logit - M[dst][h]); DEN[dst][h] += w;
// ACC[dst][h*64+c] += w[h] * H[src][h*64+c].  One wave per edge.
// Lane l handles features l*4..l*4+3 (head = l/16).
// ---------------------------------------------------------------------------
__global__ __launch_bounds__(256) void edge_scatter_k(
    const int* __restrict__ ei, const float* __restrict__ AS,
    const float* __restrict__ AD, const float* __restrict__ M,
    const float* __restrict__ H, float* __restrict__ ACC, float* __restrict__ DEN)
{
    int wave = threadIdx.x >> 6;
    int lane = threadIdx.x & 63;
    long e = (long)blockIdx.x * 4 + wave;
    if (e >= ETOT) return;
    int src, dst;
    if (e < EE) { src = ei[e]; dst = ei[EE + e]; }
    else        { src = dst = (int)(e - EE); }

    float4 s4 = *reinterpret_cast<const float4*>(AS + (size_t)src * 4);
    float4 d4 = *reinterpret_cast<const float4*>(AD + (size_t)dst * 4);
    float4 m4 = *reinterpret_cast<const float4*>(M + (size_t)dst * 4);
    float w0 = __expf(lrelu(s4.x + d4.x) - m4.x);
    float w1 = __expf(lrelu(s4.y + d4.y) - m4.y);
    float w2 = __expf(lrelu(s4.z + d4.z) - m4.z);
    float w3 = __expf(lrelu(s4.w + d4.w) - m4.w);

    if (lane == 0) {
        atomicAdd(DEN + (size_t)dst * 4 + 0, w0);
        atomicAdd(DEN + (size_t)dst * 4 + 1, w1);
        atomicAdd(DEN + (size_t)dst * 4 + 2, w2);
        atomicAdd(DEN + (size_t)dst * 4 + 3, w3);
    }

    float wq = lane < 16 ? w0 : lane < 32 ? w1 : lane < 48 ? w2 : w3;
    float4 h4 = *reinterpret_cast<const float4*>(H + (size_t)src * 256 + lane * 4);
    float* ap = ACC + (size_t)dst * 256 + lane * 4;
    atomicAdd(ap + 0, wq * h4.x);
    atomicAdd(ap + 1, wq * h4.y);
    atomicAdd(ap + 2, wq * h4.z);
    atomicAdd(ap + 3, wq * h4.w);
}

// ---------------------------------------------------------------------------
// Layer-1 finalize: ACC = relu(ACC / DEN + b1), in place. Grid NN x 256.
// ---------------------------------------------------------------------------
__global__ __launch_bounds__(256) void finalize1_k(
    float* __restrict__ ACC, const float* __restrict__ DEN, const float* __restrict__ b1)
{
    int i = blockIdx.x * 256 + threadIdx.x;
    int n = i >> 8, j = i & 255;
    float v = ACC[i] / DEN[n * 4 + (j >> 6)] + b1[j];
    ACC[i] = v > 0.f ? v : 0.f;
}

// ---------------------------------------------------------------------------
// Layer-2 finalize: OUT += 0.25 * sum_h ACC[n][h*64+c] / DEN[n][h].
// OUT already holds root@Wr.T + br + b2. Grid (NN*64/256) x 256.
// ---------------------------------------------------------------------------
__global__ __launch_bounds__(256) void finalize2_k(
    const float* __restrict__ ACC, const float* __restrict__ DEN, float* __restrict__ OUT)
{
    int i = blockIdx.x * 256 + threadIdx.x;
    int n = i >> 6, c = i & 63;
    float4 dn = *reinterpret_cast<const float4*>(DEN + (size_t)n * 4);
    const float* a = ACC + (size_t)n * 256 + c;
    float s = a[0] / dn.x + a[64] / dn.y + a[128] / dn.z + a[192] / dn.w;
    OUT[i] += 0.25f * s;
}

// ---------------------------------------------------------------------------
extern "C" void kernel_launch(void* const* d_in, const int* in_sizes, int n_in,
                              void* d_out, int out_size, void* d_ws, size_t ws_size,
                              hipStream_t stream) {
    const float* x    = (const float*)d_in[0];
    const float* root = (const float*)d_in[1];
    const int*   ei   = (const int*)  d_in[2];
    const float* W1   = (const float*)d_in[3];
    const float* as1  = (const float*)d_in[4];
    const float* ad1  = (const float*)d_in[5];
    const float* b1   = (const float*)d_in[6];
    const float* W2   = (const float*)d_in[7];
    const float* as2  = (const float*)d_in[8];
    const float* ad2  = (const float*)d_in[9];
    const float* b2   = (const float*)d_in[10];
    const float* Wr   = (const float*)d_in[11];
    const float* br   = (const float*)d_in[12];
    float* out = (float*)d_out;

    float* ws  = (float*)d_ws;
    float* H   = ws;                               // N*256
    float* ACC = H   + (size_t)NN * 256;           // N*256
    float* AS  = ACC + (size_t)NN * 256;           // N*4
    float* AD  = AS  + (size_t)NN * 4;             // N*4
    float* M   = AD  + (size_t)NN * 4;             // N*4
    float* DEN = M   + (size_t)NN * 4;             // N*4

    const int gemmGx = (NN + BM - 1) / BM;         // 782
    const int egrid  = (ETOT + 255) / 256;
    const int sgrid  = (ETOT + 3) / 4;

    // ----- layer 1 -----
    gemm_tn<<<dim3(gemmGx, 4), 256, 0, stream>>>(x, W1, H, NN, 256, nullptr, nullptr);
    alphas_k<<<NN / 4, 256, 0, stream>>>(H, as1, ad1, AS, AD);
    init_k<<<NN, 256, 0, stream>>>(ACC, M, DEN);
    edge_max_k<<<egrid, 256, 0, stream>>>(ei, AS, AD, M);
    edge_scatter_k<<<sgrid, 256, 0, stream>>>(ei, AS, AD, M, H, ACC, DEN);
    finalize1_k<<<NN, 256, 0, stream>>>(ACC, DEN, b1);

    // ----- layer 2 (input = ACC, H reused for H2) -----
    gemm_tn<<<dim3(gemmGx, 4), 256, 0, stream>>>(ACC, W2, H, NN, 256, nullptr, nullptr);
    alphas_k<<<NN / 4, 256, 0, stream>>>(H, as2, ad2, AS, AD);
    init_k<<<NN, 256, 0, stream>>>(ACC, M, DEN);
    edge_max_k<<<egrid, 256, 0, stream>>>(ei, AS, AD, M);
    edge_scatter_k<<<sgrid, 256, 0, stream>>>(ei, AS, AD, M, H, ACC, DEN);

    // ----- root skip + biases directly into d_out, then add head-mean -----
    gemm_tn<<<dim3(gemmGx, 1), 256, 0, stream>>>(root, Wr, out, NN, 64, br, b2);
    finalize2_k<<<(NN * 64) / 256, 256, 0, stream>>>(ACC, DEN, out);
}

// Round 2
// 881.203 us; speedup vs baseline: 7.5748x; 7.5748x over previous
//
#include <hip/hip_runtime.h>
#include <hip/hip_bf16.h>
#include <math.h>

#define NN   50000
#define EE   800000
#define ETOT (EE + NN)
#define KDIM 256
#define HEADS 4
#define HIDD 64

// ---------------------------------------------------------------------------
// GEMM: C[m][c] = sum_k A[m][k] * W[c][k]  (+ optional bias0[c] + bias1[c])
// A: [Mrows, 256], W: [ncols, 256], C: [Mrows, ncols]; ncols multiple of 64.
// Tile 64x64, BK=64, 256 threads, 4x4 register tile per thread.
// ---------------------------------------------------------------------------
#define BM 64
#define BN 64
#define BKT 64

__global__ __launch_bounds__(256) void gemm_tn(
    const float* __restrict__ A, const float* __restrict__ W,
    float* __restrict__ C, int Mrows, int ncols,
    const float* __restrict__ bias0, const float* __restrict__ bias1)
{
    __shared__ float As[BKT][BM + 4];
    __shared__ float Bs[BKT][BN + 4];

    const int tid = threadIdx.x;
    const int rg = tid >> 4;
    const int cg = tid & 15;
    const int n0 = blockIdx.x * BM;
    const int c0 = blockIdx.y * BN;

    float acc[4][4];
    #pragma unroll
    for (int i = 0; i < 4; i++)
        #pragma unroll
        for (int j = 0; j < 4; j++) acc[i][j] = 0.f;

    for (int k0 = 0; k0 < KDIM; k0 += BKT) {
        #pragma unroll
        for (int i = 0; i < 4; i++) {
            int f  = tid + 256 * i;
            int r  = f >> 4;
            int kq = f & 15;
            float4 v = make_float4(0.f, 0.f, 0.f, 0.f);
            int gr = n0 + r;
            if (gr < Mrows)
                v = *reinterpret_cast<const float4*>(A + (size_t)gr * KDIM + k0 + kq * 4);
            As[kq * 4 + 0][r] = v.x;
            As[kq * 4 + 1][r] = v.y;
            As[kq * 4 + 2][r] = v.z;
            As[kq * 4 + 3][r] = v.w;
        }
        #pragma unroll
        for (int i = 0; i < 4; i++) {
            int f  = tid + 256 * i;
            int c  = f >> 4;
            int kq = f & 15;
            float4 v = *reinterpret_cast<const float4*>(W + (size_t)(c0 + c) * KDIM + k0 + kq * 4);
            Bs[kq * 4 + 0][c] = v.x;
            Bs[kq * 4 + 1][c] = v.y;
            Bs[kq * 4 + 2][c] = v.z;
            Bs[kq * 4 + 3][c] = v.w;
        }
        __syncthreads();

        #pragma unroll 16
        for (int k = 0; k < BKT; k++) {
            float4 a = *reinterpret_cast<const float4*>(&As[k][rg * 4]);
            float4 b = *reinterpret_cast<const float4*>(&Bs[k][cg * 4]);
            acc[0][0] += a.x * b.x; acc[0][1] += a.x * b.y; acc[0][2] += a.x * b.z; acc[0][3] += a.x * b.w;
            acc[1][0] += a.y * b.x; acc[1][1] += a.y * b.y; acc[1][2] += a.y * b.z; acc[1][3] += a.y * b.w;
            acc[2][0] += a.z * b.x; acc[2][1] += a.z * b.y; acc[2][2] += a.z * b.z; acc[2][3] += a.z * b.w;
            acc[3][0] += a.w * b.x; acc[3][1] += a.w * b.y; acc[3][2] += a.w * b.z; acc[3][3] += a.w * b.w;
        }
        __syncthreads();
    }

    #pragma unroll
    for (int i = 0; i < 4; i++) {
        int gr = n0 + rg * 4 + i;
        if (gr >= Mrows) continue;
        float4 v = make_float4(acc[i][0], acc[i][1], acc[i][2], acc[i][3]);
        int gc = c0 + cg * 4;
        if (bias0) { v.x += bias0[gc + 0]; v.y += bias0[gc + 1]; v.z += bias0[gc + 2]; v.w += bias0[gc + 3]; }
        if (bias1) { v.x += bias1[gc + 0]; v.y += bias1[gc + 1]; v.z += bias1[gc + 2]; v.w += bias1[gc + 3]; }
        *reinterpret_cast<float4*>(C + (size_t)gr * ncols + gc) = v;
    }
}

// ---------------------------------------------------------------------------
// Per-node attention terms: AS[n][h] = sum_c H[n][h*64+c]*a_src[h*64+c], same AD.
// ---------------------------------------------------------------------------
__global__ __launch_bounds__(256) void alphas_k(
    const float* __restrict__ H, const float* __restrict__ a_src,
    const float* __restrict__ a_dst, float* __restrict__ AS, float* __restrict__ AD)
{
    int wave = threadIdx.x >> 6;
    int lane = threadIdx.x & 63;
    int n = blockIdx.x * 4 + wave;
    if (n >= NN) return;
    const float* hrow = H + (size_t)n * 256;
    #pragma unroll
    for (int h = 0; h < HEADS; h++) {
        float v = hrow[h * 64 + lane];
        float s = v * a_src[h * 64 + lane];
        float d = v * a_dst[h * 64 + lane];
        #pragma unroll
        for (int m = 32; m >= 1; m >>= 1) {
            s += __shfl_xor(s, m, 64);
            d += __shfl_xor(d, m, 64);
        }
        if (lane == 0) { AS[n * 4 + h] = s; AD[n * 4 + h] = d; }
    }
}

__device__ __forceinline__ float lrelu(float x) { return x >= 0.f ? x : 0.2f * x; }

// ---------------------------------------------------------------------------
// CSR build: deg count -> exclusive scan -> fill (src indices bucketed by dst)
// ---------------------------------------------------------------------------
__global__ __launch_bounds__(256) void zero_deg_k(int* __restrict__ deg)
{
    int i = blockIdx.x * 256 + threadIdx.x;
    if (i < NN) deg[i] = 0;
}

__global__ __launch_bounds__(256) void count_deg_k(const int* __restrict__ ei, int* __restrict__ deg)
{
    int e = blockIdx.x * 256 + threadIdx.x;
    if (e >= ETOT) return;
    int dst = (e < EE) ? ei[EE + e] : e - EE;
    atomicAdd(deg + dst, 1);
}

#define CHUNK 196   // 256*196 = 50176 >= NN

__global__ __launch_bounds__(256) void scan_k(
    const int* __restrict__ deg, int* __restrict__ rowptr, int* __restrict__ cursor)
{
    __shared__ int pref[256];
    int t = threadIdx.x;
    int beg = t * CHUNK, end = min(beg + CHUNK, NN);
    int s = 0;
    for (int i = beg; i < end; i++) s += deg[i];
    pref[t] = s;
    __syncthreads();
    if (t == 0) {
        int run = 0;
        for (int i = 0; i < 256; i++) { int v = pref[i]; pref[i] = run; run += v; }
    }
    __syncthreads();
    int run = pref[t];
    for (int i = beg; i < end; i++) {
        rowptr[i] = run;
        cursor[i] = run;
        run += deg[i];
    }
    if (t == 255) rowptr[NN] = ETOT;
}

__global__ __launch_bounds__(256) void fill_k(
    const int* __restrict__ ei, int* __restrict__ cursor, int* __restrict__ EDG)
{
    int e = blockIdx.x * 256 + threadIdx.x;
    if (e >= ETOT) return;
    int src, dst;
    if (e < EE) { src = ei[e]; dst = ei[EE + e]; }
    else        { src = dst = e - EE; }
    int pos = atomicAdd(cursor + dst, 1);
    EDG[pos] = src;
}

// ---------------------------------------------------------------------------
// Gather-aggregate: one wave per node. Lane l: head h=l>>4, feats l*4..l*4+3.
// Pass 1: segment max of logits. Pass 2: exp-weights, denom, weighted sum of
// H rows, all in registers. MODE 1: OUT = relu(acc/den + bias) [N,256].
// MODE 2: OUT[n][c] += 0.25 * sum_h acc_h[c]/den_h   [N,64] (root skip already there).
// ---------------------------------------------------------------------------
template<int MODE>
__global__ __launch_bounds__(256) void gather_k(
    const int* __restrict__ rowptr, const int* __restrict__ EDG,
    const float* __restrict__ AS, const float* __restrict__ AD,
    const float* __restrict__ H, const float* __restrict__ bias,
    float* __restrict__ OUT)
{
    int wave = threadIdx.x >> 6;
    int lane = threadIdx.x & 63;
    int n = blockIdx.x * 4 + wave;
    if (n >= NN) return;
    int h = lane >> 4;

    int beg = rowptr[n], end = rowptr[n + 1];
    float ad = AD[(size_t)n * 4 + h];

    float m = -__builtin_inff();
    for (int e = beg; e < end; e++) {
        int src = EDG[e];
        m = fmaxf(m, lrelu(AS[(size_t)src * 4 + h] + ad));
    }

    float den = 0.f, a0 = 0.f, a1 = 0.f, a2 = 0.f, a3 = 0.f;
    for (int e = beg; e < end; e++) {
        int src = EDG[e];
        float w = __expf(lrelu(AS[(size_t)src * 4 + h] + ad) - m);
        den += w;
        float4 h4 = *reinterpret_cast<const float4*>(H + (size_t)src * 256 + lane * 4);
        a0 += w * h4.x; a1 += w * h4.y; a2 += w * h4.z; a3 += w * h4.w;
    }
    float inv = 1.f / den;   // self-loop guarantees den > 0

    if (MODE == 1) {
        float4 b = *reinterpret_cast<const float4*>(bias + lane * 4);
        float4 v;
        v.x = fmaxf(a0 * inv + b.x, 0.f);
        v.y = fmaxf(a1 * inv + b.y, 0.f);
        v.z = fmaxf(a2 * inv + b.z, 0.f);
        v.w = fmaxf(a3 * inv + b.w, 0.f);
        *reinterpret_cast<float4*>(OUT + (size_t)n * 256 + lane * 4) = v;
    } else {
        float v0 = a0 * inv, v1 = a1 * inv, v2 = a2 * inv, v3 = a3 * inv;
        #pragma unroll
        for (int msk = 16; msk <= 32; msk <<= 1) {
            v0 += __shfl_xor(v0, msk, 64);
            v1 += __shfl_xor(v1, msk, 64);
            v2 += __shfl_xor(v2, msk, 64);
            v3 += __shfl_xor(v3, msk, 64);
        }
        if (lane < 16) {
            float4* o = reinterpret_cast<float4*>(OUT + (size_t)n * 64 + lane * 4);
            float4 cur = *o;
            cur.x += 0.25f * v0;
            cur.y += 0.25f * v1;
            cur.z += 0.25f * v2;
            cur.w += 0.25f * v3;
            *o = cur;
        }
    }
}

// ---------------------------------------------------------------------------
extern "C" void kernel_launch(void* const* d_in, const int* in_sizes, int n_in,
                              void* d_out, int out_size, void* d_ws, size_t ws_size,
                              hipStream_t stream) {
    const float* x    = (const float*)d_in[0];
    const float* root = (const float*)d_in[1];
    const int*   ei   = (const int*)  d_in[2];
    const float* W1   = (const float*)d_in[3];
    const float* as1  = (const float*)d_in[4];
    const float* ad1  = (const float*)d_in[5];
    const float* b1   = (const float*)d_in[6];
    const float* W2   = (const float*)d_in[7];
    const float* as2  = (const float*)d_in[8];
    const float* ad2  = (const float*)d_in[9];
    const float* b2   = (const float*)d_in[10];
    const float* Wr   = (const float*)d_in[11];
    const float* br   = (const float*)d_in[12];
    float* out = (float*)d_out;

    float* ws  = (float*)d_ws;
    float* H   = ws;                               // N*256
    float* X2  = H   + (size_t)NN * 256;           // N*256 (layer-1 output)
    float* AS  = X2  + (size_t)NN * 256;           // N*4
    float* AD  = AS  + (size_t)NN * 4;             // N*4
    int*   deg    = (int*)(AD + (size_t)NN * 4);   // N
    int*   rowptr = deg + NN;                      // N+1
    int*   cursor = rowptr + NN + 1;               // N
    int*   EDG    = cursor + NN;                   // ETOT

    const int gemmGx = (NN + BM - 1) / BM;
    const int egrid  = (ETOT + 255) / 256;
    const int ngrid  = (NN + 255) / 256;
    const int wgrid  = (NN + 3) / 4;

    // ----- CSR build (graph is shared by both layers) -----
    zero_deg_k<<<ngrid, 256, 0, stream>>>(deg);
    count_deg_k<<<egrid, 256, 0, stream>>>(ei, deg);
    scan_k<<<1, 256, 0, stream>>>(deg, rowptr, cursor);
    fill_k<<<egrid, 256, 0, stream>>>(ei, cursor, EDG);

    // ----- layer 1 -----
    gemm_tn<<<dim3(gemmGx, 4), 256, 0, stream>>>(x, W1, H, NN, 256, nullptr, nullptr);
    alphas_k<<<wgrid, 256, 0, stream>>>(H, as1, ad1, AS, AD);
    gather_k<1><<<wgrid, 256, 0, stream>>>(rowptr, EDG, AS, AD, H, b1, X2);

    // ----- layer 2 -----
    gemm_tn<<<dim3(gemmGx, 4), 256, 0, stream>>>(X2, W2, H, NN, 256, nullptr, nullptr);
    alphas_k<<<wgrid, 256, 0, stream>>>(H, as2, ad2, AS, AD);

    // root skip + biases into d_out, then add head-mean of layer-2 aggregation
    gemm_tn<<<dim3(gemmGx, 1), 256, 0, stream>>>(root, Wr, out, NN, 64, br, b2);
    gather_k<2><<<wgrid, 256, 0, stream>>>(rowptr, EDG, AS, AD, H, nullptr, out);
}

// Round 3
// 746.978 us; speedup vs baseline: 8.9359x; 1.1797x over previous
//
#include <hip/hip_runtime.h>
#include <hip/hip_bf16.h>
#include <math.h>

#define NN   50000
#define EE   800000
#define ETOT (EE + NN)
#define KDIM 256
#define HEADS 4
#define HIDD 64

typedef float  f32x4  __attribute__((ext_vector_type(4)));
typedef short  bf16x8 __attribute__((ext_vector_type(8)));

__device__ __forceinline__ float b2f(unsigned short u) {
    union { float f; unsigned int i; } v; v.i = (unsigned int)u << 16; return v.f;
}
__device__ __forceinline__ unsigned short f2b(float f) {
    union { float f; unsigned int i; } v; v.f = f;
    return (unsigned short)((v.i + 0x7fffu + ((v.i >> 16) & 1u)) >> 16);
}
__device__ __forceinline__ float lrelu(float x) { return x >= 0.f ? x : 0.2f * x; }

// ---------------------------------------------------------------------------
// fp32 -> bf16 cast, 4 elems/thread. n multiple of 4.
// ---------------------------------------------------------------------------
__global__ __launch_bounds__(256) void cast_k(
    const float* __restrict__ in, unsigned short* __restrict__ out, int n)
{
    int i = (blockIdx.x * 256 + threadIdx.x) * 4;
    if (i >= n) return;
    float4 v = *reinterpret_cast<const float4*>(in + i);
    ushort4 o;
    o.x = f2b(v.x); o.y = f2b(v.y); o.z = f2b(v.z); o.w = f2b(v.w);
    *reinterpret_cast<ushort4*>(out + i) = o;
}

// ---------------------------------------------------------------------------
// bf16 MFMA GEMM (TN): C[m][c] = sum_k A[m][k] * W[c][k], K=256, ncols=256.
// A [Mrows,256] bf16, W [256,256] bf16 (row-major, k contiguous), C bf16.
// One wave per 16-row tile, all 256 cols (16 acc tiles). 4 waves/block.
// a_frag: lane holds A[m0+(l&15)][k0+(l>>4)*8 + 0..7] (16B contiguous).
// b_frag: lane holds W[c0+(l&15)][k0+(l>>4)*8 + 0..7] (16B contiguous).
// D: lane holds D[m0+(l>>4)*4+reg][c0+(l&15)].
// ---------------------------------------------------------------------------
__global__ __launch_bounds__(256) void gemm_mfma(
    const unsigned short* __restrict__ A, const unsigned short* __restrict__ W,
    unsigned short* __restrict__ C, int Mrows)
{
    int wid  = threadIdx.x >> 6;
    int lane = threadIdx.x & 63;
    int m0 = (blockIdx.x * 4 + wid) * 16;
    if (m0 >= Mrows) return;
    int cl = lane & 15;
    int kg = lane >> 4;

    int arow = m0 + cl; if (arow >= Mrows) arow = Mrows - 1;
    const unsigned short* ap = A + (size_t)arow * KDIM + kg * 8;

    f32x4 acc[16];
    #pragma unroll
    for (int ct = 0; ct < 16; ct++) acc[ct] = (f32x4)(0.f);

    for (int k0 = 0; k0 < KDIM; k0 += 32) {
        bf16x8 a = *reinterpret_cast<const bf16x8*>(ap + k0);
        #pragma unroll
        for (int ct = 0; ct < 16; ct++) {
            bf16x8 b = *reinterpret_cast<const bf16x8*>(
                W + (size_t)(ct * 16 + cl) * KDIM + k0 + kg * 8);
            acc[ct] = __builtin_amdgcn_mfma_f32_16x16x32_bf16(a, b, acc[ct], 0, 0, 0);
        }
    }

    #pragma unroll
    for (int ct = 0; ct < 16; ct++) {
        #pragma unroll
        for (int r = 0; r < 4; r++) {
            int n = m0 + kg * 4 + r;
            if (n < Mrows)
                C[(size_t)n * KDIM + ct * 16 + cl] = f2b(acc[ct][r]);
        }
    }
}

// ---------------------------------------------------------------------------
// Per-node attention terms from bf16 H.
// ---------------------------------------------------------------------------
__global__ __launch_bounds__(256) void alphas_k(
    const unsigned short* __restrict__ H, const float* __restrict__ a_src,
    const float* __restrict__ a_dst, float* __restrict__ AS, float* __restrict__ AD)
{
    int wave = threadIdx.x >> 6;
    int lane = threadIdx.x & 63;
    int n = blockIdx.x * 4 + wave;
    if (n >= NN) return;
    const unsigned short* hrow = H + (size_t)n * 256;
    #pragma unroll
    for (int h = 0; h < HEADS; h++) {
        float v = b2f(hrow[h * 64 + lane]);
        float s = v * a_src[h * 64 + lane];
        float d = v * a_dst[h * 64 + lane];
        #pragma unroll
        for (int m = 32; m >= 1; m >>= 1) {
            s += __shfl_xor(s, m, 64);
            d += __shfl_xor(d, m, 64);
        }
        if (lane == 0) { AS[n * 4 + h] = s; AD[n * 4 + h] = d; }
    }
}

// ---------------------------------------------------------------------------
// CSR build
// ---------------------------------------------------------------------------
__global__ __launch_bounds__(256) void zero_deg_k(int* __restrict__ deg)
{
    int i = blockIdx.x * 256 + threadIdx.x;
    if (i < NN) deg[i] = 0;
}

__global__ __launch_bounds__(256) void count_deg_k(const int* __restrict__ ei, int* __restrict__ deg)
{
    int e = blockIdx.x * 256 + threadIdx.x;
    if (e >= ETOT) return;
    int dst = (e < EE) ? ei[EE + e] : e - EE;
    atomicAdd(deg + dst, 1);
}

#define CHUNK 196   // 256*196 = 50176 >= NN

__global__ __launch_bounds__(256) void scan_k(
    const int* __restrict__ deg, int* __restrict__ rowptr, int* __restrict__ cursor)
{
    __shared__ int pref[256];
    int t = threadIdx.x;
    int beg = t * CHUNK, end = min(beg + CHUNK, NN);
    int s = 0;
    for (int i = beg; i < end; i++) s += deg[i];
    pref[t] = s;
    __syncthreads();
    if (t == 0) {
        int run = 0;
        for (int i = 0; i < 256; i++) { int v = pref[i]; pref[i] = run; run += v; }
    }
    __syncthreads();
    int run = pref[t];
    for (int i = beg; i < end; i++) {
        rowptr[i] = run;
        cursor[i] = run;
        run += deg[i];
    }
    if (t == 255) rowptr[NN] = ETOT;
}

__global__ __launch_bounds__(256) void fill_k(
    const int* __restrict__ ei, int* __restrict__ cursor, int* __restrict__ EDG)
{
    int e = blockIdx.x * 256 + threadIdx.x;
    if (e >= ETOT) return;
    int src, dst;
    if (e < EE) { src = ei[e]; dst = ei[EE + e]; }
    else        { src = dst = e - EE; }
    int pos = atomicAdd(cursor + dst, 1);
    EDG[pos] = src;
}

// ---------------------------------------------------------------------------
// Gather-aggregate from bf16 H. One wave/node; lane l: head h=l>>4, feats l*4..+3.
// MODE 1: OUT(bf16) = relu(acc/den + bias) [N,256].
// MODE 2: OUTF(f32)[n][c] += 0.25 * sum_h acc_h[c]/den_h [N,64].
// ---------------------------------------------------------------------------
template<int MODE>
__global__ __launch_bounds__(256) void gather_k(
    const int* __restrict__ rowptr, const int* __restrict__ EDG,
    const float* __restrict__ AS, const float* __restrict__ AD,
    const unsigned short* __restrict__ H, const float* __restrict__ bias,
    unsigned short* __restrict__ OUT, float* __restrict__ OUTF)
{
    int wave = threadIdx.x >> 6;
    int lane = threadIdx.x & 63;
    int n = blockIdx.x * 4 + wave;
    if (n >= NN) return;
    int h = lane >> 4;

    int beg = rowptr[n], end = rowptr[n + 1];
    float ad = AD[(size_t)n * 4 + h];

    float m = -__builtin_inff();
    for (int e = beg; e < end; e++) {
        int src = EDG[e];
        m = fmaxf(m, lrelu(AS[(size_t)src * 4 + h] + ad));
    }

    float den = 0.f, a0 = 0.f, a1 = 0.f, a2 = 0.f, a3 = 0.f;
    for (int e = beg; e < end; e++) {
        int src = EDG[e];
        float w = __expf(lrelu(AS[(size_t)src * 4 + h] + ad) - m);
        den += w;
        ushort4 hv = *reinterpret_cast<const ushort4*>(H + (size_t)src * 256 + lane * 4);
        a0 += w * b2f(hv.x); a1 += w * b2f(hv.y); a2 += w * b2f(hv.z); a3 += w * b2f(hv.w);
    }
    float inv = 1.f / den;   // self-loop guarantees den > 0

    if (MODE == 1) {
        float4 b = *reinterpret_cast<const float4*>(bias + lane * 4);
        ushort4 o;
        o.x = f2b(fmaxf(a0 * inv + b.x, 0.f));
        o.y = f2b(fmaxf(a1 * inv + b.y, 0.f));
        o.z = f2b(fmaxf(a2 * inv + b.z, 0.f));
        o.w = f2b(fmaxf(a3 * inv + b.w, 0.f));
        *reinterpret_cast<ushort4*>(OUT + (size_t)n * 256 + lane * 4) = o;
    } else {
        float v0 = a0 * inv, v1 = a1 * inv, v2 = a2 * inv, v3 = a3 * inv;
        #pragma unroll
        for (int msk = 16; msk <= 32; msk <<= 1) {
            v0 += __shfl_xor(v0, msk, 64);
            v1 += __shfl_xor(v1, msk, 64);
            v2 += __shfl_xor(v2, msk, 64);
            v3 += __shfl_xor(v3, msk, 64);
        }
        if (lane < 16) {
            float4* o = reinterpret_cast<float4*>(OUTF + (size_t)n * 64 + lane * 4);
            float4 cur = *o;
            cur.x += 0.25f * v0;
            cur.y += 0.25f * v1;
            cur.z += 0.25f * v2;
            cur.w += 0.25f * v3;
            *o = cur;
        }
    }
}

// ---------------------------------------------------------------------------
// fp32 vector GEMM for the root skip (64 cols): OUT = root@Wr.T + br + b2.
// ---------------------------------------------------------------------------
#define BM 64
#define BN 64
#define BKT 64

__global__ __launch_bounds__(256) void gemm_tn(
    const float* __restrict__ A, const float* __restrict__ W,
    float* __restrict__ C, int Mrows, int ncols,
    const float* __restrict__ bias0, const float* __restrict__ bias1)
{
    __shared__ float As[BKT][BM + 4];
    __shared__ float Bs[BKT][BN + 4];

    const int tid = threadIdx.x;
    const int rg = tid >> 4;
    const int cg = tid & 15;
    const int n0 = blockIdx.x * BM;
    const int c0 = blockIdx.y * BN;

    float acc[4][4];
    #pragma unroll
    for (int i = 0; i < 4; i++)
        #pragma unroll
        for (int j = 0; j < 4; j++) acc[i][j] = 0.f;

    for (int k0 = 0; k0 < KDIM; k0 += BKT) {
        #pragma unroll
        for (int i = 0; i < 4; i++) {
            int f  = tid + 256 * i;
            int r  = f >> 4;
            int kq = f & 15;
            float4 v = make_float4(0.f, 0.f, 0.f, 0.f);
            int gr = n0 + r;
            if (gr < Mrows)
                v = *reinterpret_cast<const float4*>(A + (size_t)gr * KDIM + k0 + kq * 4);
            As[kq * 4 + 0][r] = v.x;
            As[kq * 4 + 1][r] = v.y;
            As[kq * 4 + 2][r] = v.z;
            As[kq * 4 + 3][r] = v.w;
        }
        #pragma unroll
        for (int i = 0; i < 4; i++) {
            int f  = tid + 256 * i;
            int c  = f >> 4;
            int kq = f & 15;
            float4 v = *reinterpret_cast<const float4*>(W + (size_t)(c0 + c) * KDIM + k0 + kq * 4);
            Bs[kq * 4 + 0][c] = v.x;
            Bs[kq * 4 + 1][c] = v.y;
            Bs[kq * 4 + 2][c] = v.z;
            Bs[kq * 4 + 3][c] = v.w;
        }
        __syncthreads();

        #pragma unroll 16
        for (int k = 0; k < BKT; k++) {
            float4 a = *reinterpret_cast<const float4*>(&As[k][rg * 4]);
            float4 b = *reinterpret_cast<const float4*>(&Bs[k][cg * 4]);
            acc[0][0] += a.x * b.x; acc[0][1] += a.x * b.y; acc[0][2] += a.x * b.z; acc[0][3] += a.x * b.w;
            acc[1][0] += a.y * b.x; acc[1][1] += a.y * b.y; acc[1][2] += a.y * b.z; acc[1][3] += a.y * b.w;
            acc[2][0] += a.z * b.x; acc[2][1] += a.z * b.y; acc[2][2] += a.z * b.z; acc[2][3] += a.z * b.w;
            acc[3][0] += a.w * b.x; acc[3][1] += a.w * b.y; acc[3][2] += a.w * b.z; acc[3][3] += a.w * b.w;
        }
        __syncthreads();
    }

    #pragma unroll
    for (int i = 0; i < 4; i++) {
        int gr = n0 + rg * 4 + i;
        if (gr >= Mrows) continue;
        float4 v = make_float4(acc[i][0], acc[i][1], acc[i][2], acc[i][3]);
        int gc = c0 + cg * 4;
        if (bias0) { v.x += bias0[gc + 0]; v.y += bias0[gc + 1]; v.z += bias0[gc + 2]; v.w += bias0[gc + 3]; }
        if (bias1) { v.x += bias1[gc + 0]; v.y += bias1[gc + 1]; v.z += bias1[gc + 2]; v.w += bias1[gc + 3]; }
        *reinterpret_cast<float4*>(C + (size_t)gr * ncols + gc) = v;
    }
}

// ---------------------------------------------------------------------------
extern "C" void kernel_launch(void* const* d_in, const int* in_sizes, int n_in,
                              void* d_out, int out_size, void* d_ws, size_t ws_size,
                              hipStream_t stream) {
    const float* x    = (const float*)d_in[0];
    const float* root = (const float*)d_in[1];
    const int*   ei   = (const int*)  d_in[2];
    const float* W1   = (const float*)d_in[3];
    const float* as1  = (const float*)d_in[4];
    const float* ad1  = (const float*)d_in[5];
    const float* b1   = (const float*)d_in[6];
    const float* W2   = (const float*)d_in[7];
    const float* as2  = (const float*)d_in[8];
    const float* ad2  = (const float*)d_in[9];
    const float* b2   = (const float*)d_in[10];
    const float* Wr   = (const float*)d_in[11];
    const float* br   = (const float*)d_in[12];
    float* out = (float*)d_out;

    unsigned short* xb  = (unsigned short*)d_ws;             // N*256
    unsigned short* Hb  = xb  + (size_t)NN * 256;            // N*256
    unsigned short* X2b = Hb  + (size_t)NN * 256;            // N*256
    unsigned short* w1b = X2b + (size_t)NN * 256;            // 65536
    unsigned short* w2b = w1b + 65536;                       // 65536
    float* AS = (float*)(w2b + 65536);                       // N*4
    float* AD = AS + (size_t)NN * 4;                         // N*4
    int*   deg    = (int*)(AD + (size_t)NN * 4);             // N
    int*   rowptr = deg + NN;                                // N+1
    int*   cursor = rowptr + NN + 1;                         // N
    int*   EDG    = cursor + NN;                             // ETOT

    const int egrid  = (ETOT + 255) / 256;
    const int ngrid  = (NN + 255) / 256;
    const int wgrid  = (NN + 3) / 4;
    const int mgrid  = (NN + 63) / 64;       // gemm_mfma: 4 waves x 16 rows

    // ----- CSR build -----
    zero_deg_k<<<ngrid, 256, 0, stream>>>(deg);
    count_deg_k<<<egrid, 256, 0, stream>>>(ei, deg);
    scan_k<<<1, 256, 0, stream>>>(deg, rowptr, cursor);
    fill_k<<<egrid, 256, 0, stream>>>(ei, cursor, EDG);

    // ----- casts -----
    cast_k<<<(NN * 256 / 4 + 255) / 256, 256, 0, stream>>>(x, xb, NN * 256);
    cast_k<<<(65536 / 4 + 255) / 256, 256, 0, stream>>>(W1, w1b, 65536);
    cast_k<<<(65536 / 4 + 255) / 256, 256, 0, stream>>>(W2, w2b, 65536);

    // ----- layer 1 -----
    gemm_mfma<<<mgrid, 256, 0, stream>>>(xb, w1b, Hb, NN);
    alphas_k<<<wgrid, 256, 0, stream>>>(Hb, as1, ad1, AS, AD);
    gather_k<1><<<wgrid, 256, 0, stream>>>(rowptr, EDG, AS, AD, Hb, b1, X2b, nullptr);

    // ----- layer 2 -----
    gemm_mfma<<<mgrid, 256, 0, stream>>>(X2b, w2b, Hb, NN);
    alphas_k<<<wgrid, 256, 0, stream>>>(Hb, as2, ad2, AS, AD);

    // root skip + biases into d_out (fp32), then add head-mean of layer-2 agg
    gemm_tn<<<dim3((NN + BM - 1) / BM, 1), 256, 0, stream>>>(root, Wr, out, NN, 64, br, b2);
    gather_k<2><<<wgrid, 256, 0, stream>>>(rowptr, EDG, AS, AD, Hb, nullptr, nullptr, out);
}